// Round 2
// baseline (8548.036 us; speedup 1.0000x reference)
//
#include <hip/hip_runtime.h>
#include <hip/hip_bf16.h>
#include <math.h>

#define BB 64
#define SS 64
#define DIN 512
#define DA 512
#define DM 2048
#define MM 25
#define NH 8
#define HD 64
#define NS 512
#define NOUT 1000
#define TT 50
#define HN 32

// ---------------- workspace layout (floats) ----------------
static const size_t OFF_K     = 0;
static const size_t OFF_V     = OFF_K + (size_t)BB*SS*DA;          // 2,097,152
static const size_t OFF_WFK   = OFF_V + (size_t)BB*SS*DA;
static const size_t OFF_WFV   = OFF_WFK + (size_t)DIN*DA;
static const size_t OFF_WC1   = OFF_WFV + (size_t)DIN*DA;
static const size_t OFF_WOS1  = OFF_WC1 + (size_t)NS*DA;
static const size_t OFF_BFK   = OFF_WOS1 + (size_t)DA*2*DM;
static const size_t OFF_BFV   = OFF_BFK + DA;
static const size_t OFF_BC1   = OFF_BFV + DA;
static const size_t OFF_BC2   = OFF_BC1 + DA;
static const size_t OFF_AA    = OFF_BC2 + 2*DM;
static const size_t OFF_BA    = OFF_AA + (size_t)2*BB*NS;
static const size_t OFF_AO    = OFF_BA + (size_t)2*BB*NS;
static const size_t OFF_BO    = OFF_AO + (size_t)2*BB*NS;
static const size_t OFF_QH    = OFF_BO + (size_t)2*BB*NS;
static const size_t OFF_ATT   = OFF_QH + (size_t)BB*DA;
static const size_t OFF_HPART = OFF_ATT + (size_t)BB*DA;
static const size_t OFF_TRACE = OFF_HPART + (size_t)8*BB*2*DM;
static const size_t OFF_ACT   = OFF_TRACE + (size_t)MM*DM*BB;      // act layout [d][b]
static const size_t OFF_PRED  = OFF_ACT + (size_t)DM*BB;
static const size_t OFF_END   = OFF_PRED + (size_t)BB*NOUT;

__device__ inline float gelu_tanh(float x){
    float x3 = x*x*x;
    float u = 0.7978845608028654f*(x + 0.044715f*x3);
    return 0.5f*x*(1.0f + tanhf(u));
}

// ---------------- generic 64x64-tile fp32 GEMM (setup only) ----------------
__global__ void sgemm64(const float* __restrict__ A, int lda,
                        const float* __restrict__ Bm, int ldb,
                        const float* __restrict__ bias,
                        float* __restrict__ C, int ldc, int Kdim)
{
    __shared__ float la[16][65];
    __shared__ float lb[16][64];
    int cg = blockIdx.x, rg = blockIdx.y, tid = threadIdx.x;
    int tx = tid & 15, ty = tid >> 4;
    const float* Ab = A + (size_t)rg*64*lda;
    const float* Bb = Bm + (size_t)cg*64;
    float acc[4][4] = {};
    for (int k0 = 0; k0 < Kdim; k0 += 16){
        for (int i = tid; i < 1024; i += 256){
            int r = i >> 4, kk = i & 15;
            la[kk][r] = Ab[(size_t)r*lda + k0 + kk];
        }
        for (int i = tid; i < 1024; i += 256){
            int kk = i >> 6, c = i & 63;
            lb[kk][c] = Bb[(size_t)(k0+kk)*ldb + c];
        }
        __syncthreads();
        #pragma unroll
        for (int kk = 0; kk < 16; ++kk){
            float av[4], bv[4];
            #pragma unroll
            for (int i = 0; i < 4; ++i) av[i] = la[kk][ty*4+i];
            #pragma unroll
            for (int j = 0; j < 4; ++j) bv[j] = lb[kk][tx*4+j];
            #pragma unroll
            for (int i = 0; i < 4; ++i)
                #pragma unroll
                for (int j = 0; j < 4; ++j) acc[i][j] += av[i]*bv[j];
        }
        __syncthreads();
    }
    for (int i = 0; i < 4; ++i){
        int row = rg*64 + ty*4 + i;
        for (int j = 0; j < 4; ++j){
            int col = cg*64 + tx*4 + j;
            float v = acc[i][j];
            if (bias) v += bias[col];
            C[(size_t)row*ldc + col] = v;
        }
    }
}

// out[n] = sum_k bvec[k]*W[k,n] + badd[n],  K fixed = 512
__global__ void bias_combo(const float* __restrict__ bvec, const float* __restrict__ W,
                           int ldw, const float* __restrict__ badd,
                           float* __restrict__ out, int N)
{
    int n = blockIdx.x*256 + threadIdx.x;
    if (n >= N) return;
    float acc = badd[n];
    for (int k = 0; k < 512; ++k) acc += bvec[k]*W[(size_t)k*ldw + n];
    out[n] = acc;
}

// act_t[d][b] = start_state[d]; aA=bA=0; aO=pairing(start_state); bO=1  (buffer 0)
__global__ void init_state(const float* __restrict__ ss,
                           const int* __restrict__ ilo, const int* __restrict__ iro,
                           float* __restrict__ act_t,
                           float* __restrict__ aA0, float* __restrict__ bA0,
                           float* __restrict__ aO0, float* __restrict__ bO0)
{
    int i = blockIdx.x*256 + threadIdx.x;
    if (i < BB*DM) act_t[i] = ss[i >> 6];
    if (i < BB*NS){
        int j = i & (NS-1);
        aA0[i] = 0.f; bA0[i] = 0.f;
        aO0[i] = ss[ilo[j]]*ss[iro[j]];
        bO0[i] = 1.f;
    }
}

// fused syncA + Qh = syA@Wc1 + bc1.   grid (8 colgroups, 16 rowgroups), 256 thr
__global__ void qh_sync(const float* __restrict__ act_t,
                        const float* __restrict__ aAold, const float* __restrict__ bAold,
                        float* __restrict__ aAnew, float* __restrict__ bAnew,
                        const int* __restrict__ il, const int* __restrict__ ir,
                        const float* __restrict__ decay,
                        const float* __restrict__ Wc1, const float* __restrict__ bc1,
                        float* __restrict__ Qh)
{
    __shared__ float sy[4][NS];
    int cg = blockIdx.x, rg = blockIdx.y, tid = threadIdx.x;
    for (int i = tid; i < 4*NS; i += 256){
        int r = i >> 9, j = i & (NS-1);
        int b = rg*4 + r;
        float pair = act_t[(size_t)il[j]*BB + b] * act_t[(size_t)ir[j]*BB + b];
        float rr = expf(-fminf(fmaxf(decay[j], 0.f), 15.f));
        float a  = rr*aAold[b*NS + j] + pair;
        float be = rr*bAold[b*NS + j] + 1.f;
        sy[r][j] = a * rsqrtf(be);
        if (cg == 0){ aAnew[b*NS + j] = a; bAnew[b*NS + j] = be; }
    }
    __syncthreads();
    int c = tid & 63, r = tid >> 6;
    int col = cg*64 + c;
    float acc = bc1[col];
    #pragma unroll 8
    for (int k = 0; k < NS; ++k) acc += sy[r][k]*Wc1[(size_t)k*DA + col];
    Qh[(size_t)(rg*4 + r)*DA + col] = acc;
}

// attention per (h,b): scores over S=64, softmax, weighted V.  64 threads.
__global__ void attn_kernel(const float* __restrict__ Qh, const float* __restrict__ Kb,
                            const float* __restrict__ Vb, float* __restrict__ att)
{
    __shared__ float q[HD];
    __shared__ float kt[SS][HD+1];
    __shared__ float w[SS];
    int h = blockIdx.x, b = blockIdx.y, lane = threadIdx.x;
    q[lane] = Qh[(size_t)b*DA + h*HD + lane];
    for (int i = lane; i < SS*HD; i += 64){
        int s = i >> 6, d = i & 63;
        kt[s][d] = Kb[((size_t)(b*SS + s))*DA + h*HD + d];
    }
    __syncthreads();
    float sc = 0.f;
    #pragma unroll 8
    for (int d = 0; d < HD; ++d) sc += q[d]*kt[lane][d];
    sc *= 0.125f;   // 1/sqrt(64)
    float m = sc;
    for (int o = 32; o; o >>= 1) m = fmaxf(m, __shfl_xor(m, o, 64));
    float e = expf(sc - m);
    float sum = e;
    for (int o = 32; o; o >>= 1) sum += __shfl_xor(sum, o, 64);
    w[lane] = e / sum;
    __syncthreads();
    float o = 0.f;
    #pragma unroll 8
    for (int s = 0; s < SS; ++s) o += w[s]*Vb[((size_t)(b*SS + s))*DA + h*HD + lane];
    att[(size_t)b*DA + h*HD + lane] = o;
}

// h = att@Wos1 + act@Ws1[512:] (+bc2 later).  split-K x8 into partial buffers.
// grid (64 colgroups, 8 kchunks), 256 thr, 64x64 tile, Kchunk=320
__global__ void hgemm(const float* __restrict__ att, const float* __restrict__ act_t,
                      const float* __restrict__ Wos1, const float* __restrict__ Ws1,
                      float* __restrict__ hpart)
{
    __shared__ float la[16][65];
    __shared__ float lb[16][64];
    int cg = blockIdx.x, kc = blockIdx.y, tid = threadIdx.x;
    int tx = tid & 15, ty = tid >> 4;
    float acc[4][4] = {};
    int kbase = kc*320;
    for (int ks = 0; ks < 20; ++ks){
        int k0 = kbase + ks*16;
        if (k0 < DA){
            for (int i = tid; i < 1024; i += 256){
                int r = i >> 4, kk = i & 15;
                la[kk][r] = att[(size_t)r*DA + k0 + kk];
            }
        } else {
            for (int i = tid; i < 1024; i += 256){
                int kk = i >> 6, b = i & 63;
                la[kk][b] = act_t[(size_t)(k0 + kk - DA)*BB + b];
            }
        }
        const float* Bp = (k0 < DA) ? Wos1 : Ws1;   // Ws1 row index == k for k>=512
        for (int i = tid; i < 1024; i += 256){
            int kk = i >> 6, c = i & 63;
            lb[kk][c] = Bp[(size_t)(k0 + kk)*(2*DM) + cg*64 + c];
        }
        __syncthreads();
        #pragma unroll
        for (int kk = 0; kk < 16; ++kk){
            float av[4], bv[4];
            #pragma unroll
            for (int i = 0; i < 4; ++i) av[i] = la[kk][ty*4+i];
            #pragma unroll
            for (int j = 0; j < 4; ++j) bv[j] = lb[kk][tx*4+j];
            #pragma unroll
            for (int i = 0; i < 4; ++i)
                #pragma unroll
                for (int j = 0; j < 4; ++j) acc[i][j] += av[i]*bv[j];
        }
        __syncthreads();
    }
    float* out = hpart + (size_t)kc*BB*2*DM;
    for (int i = 0; i < 4; ++i){
        int b = ty*4 + i, col = cg*64 + tx*4;
        float4 v = make_float4(acc[i][0], acc[i][1], acc[i][2], acc[i][3]);
        *reinterpret_cast<float4*>(&out[(size_t)b*2*DM + col]) = v;
    }
}

// GLU + LayerNorm, write state into circular trace slot (layout [slot][d][b])
__global__ void gluln(const float* __restrict__ hpart, const float* __restrict__ bc2,
                      const float* __restrict__ g, const float* __restrict__ bta,
                      float* __restrict__ trace, int t)
{
    __shared__ float red[8];
    int b = blockIdx.x, tid = threadIdx.x;
    float sv[8];
    float lsum = 0.f, lsq = 0.f;
    for (int i = 0; i < 8; ++i){
        int n = tid + i*256;
        float h1 = bc2[n], h2 = bc2[DM + n];
        #pragma unroll
        for (int c = 0; c < 8; ++c){
            const float* hp = hpart + (size_t)c*BB*2*DM + (size_t)b*2*DM;
            h1 += hp[n];
            h2 += hp[DM + n];
        }
        float s = h1 * (1.f/(1.f + expf(-h2)));
        sv[i] = s; lsum += s; lsq += s*s;
    }
    for (int o = 32; o; o >>= 1){ lsum += __shfl_down(lsum, o, 64); lsq += __shfl_down(lsq, o, 64); }
    int wid = tid >> 6;
    if ((tid & 63) == 0){ red[wid] = lsum; red[4 + wid] = lsq; }
    __syncthreads();
    float tsum = red[0]+red[1]+red[2]+red[3];
    float tsq  = red[4]+red[5]+red[6]+red[7];
    float mu = tsum/DM;
    float var = tsq/DM - mu*mu;
    float inv = rsqrtf(var + 1e-5f);
    int slot = t % MM;
    float* tr = trace + (size_t)slot*DM*BB;
    for (int i = 0; i < 8; ++i){
        int n = tid + i*256;
        float st = (sv[i] - mu)*inv*g[n] + bta[n];
        tr[(size_t)n*BB + b] = st;
    }
}

// neuron-level models: per d, act[d][b] = nw2[d]·gelu(trace_window·nw1[d]+nb1[d]) + nb2[d]
__global__ void nlm(const float* __restrict__ trace, const float* __restrict__ stt,
                    const float* __restrict__ nw1, const float* __restrict__ nb1,
                    const float* __restrict__ nw2, const float* __restrict__ nb2,
                    float* __restrict__ act_t, int t)
{
    __shared__ float w1[MM][HN];
    __shared__ float tr[MM][BB];
    __shared__ float w2[HN];
    __shared__ float b1[HN];
    __shared__ float red[4][BB];
    int d = blockIdx.x, tid = threadIdx.x;
    for (int i = tid; i < MM*HN; i += 256) w1[i/HN][i%HN] = nw1[(size_t)d*MM*HN + i];
    if (tid < HN){ w2[tid] = nw2[d*HN + tid]; b1[tid] = nb1[d*HN + tid]; }
    for (int i = tid; i < MM*BB; i += 256){
        int m = i >> 6, b = i & 63;
        int time = t - (MM-1) + m;
        float v;
        if (time >= 0) v = trace[(size_t)(time % MM)*DM*BB + (size_t)d*BB + b];
        else           v = stt[(size_t)d*MM + (m + t + 1)];
        tr[m][b] = v;
    }
    __syncthreads();
    int b = tid & 63, hg = tid >> 6;
    float pa = 0.f;
    #pragma unroll
    for (int hh = 0; hh < 8; ++hh){
        int h = hg*8 + hh;
        float a = b1[h];
        #pragma unroll
        for (int m = 0; m < MM; ++m) a += tr[m][b]*w1[m][h];
        pa += gelu_tanh(a)*w2[h];
    }
    red[hg][b] = pa;
    __syncthreads();
    if (tid < 64){
        float v = red[0][tid] + red[1][tid] + red[2][tid] + red[3][tid] + nb2[d];
        act_t[(size_t)d*BB + tid] = v;
    }
}

// fused syncO + pred = syO@Wout + bout.  grid (16 colgroups, 16 rowgroups)
__global__ void pred_sync(const float* __restrict__ act_t,
                          const float* __restrict__ aOold, const float* __restrict__ bOold,
                          float* __restrict__ aOnew, float* __restrict__ bOnew,
                          const int* __restrict__ ilo, const int* __restrict__ iro,
                          const float* __restrict__ decay,
                          const float* __restrict__ Wout, const float* __restrict__ bout,
                          float* __restrict__ pred, float* __restrict__ syo_out, int t)
{
    __shared__ float sy[4][NS];
    int cg = blockIdx.x, rg = blockIdx.y, tid = threadIdx.x;
    for (int i = tid; i < 4*NS; i += 256){
        int r = i >> 9, j = i & (NS-1);
        int b = rg*4 + r;
        float pair = act_t[(size_t)ilo[j]*BB + b] * act_t[(size_t)iro[j]*BB + b];
        float rr = expf(-fminf(fmaxf(decay[j], 0.f), 15.f));
        float a  = rr*aOold[b*NS + j] + pair;
        float be = rr*bOold[b*NS + j] + 1.f;
        float s = a * rsqrtf(be);
        sy[r][j] = s;
        if (cg == 0){
            aOnew[b*NS + j] = a; bOnew[b*NS + j] = be;
            if (t == TT-1) syo_out[b*NS + j] = s;
        }
    }
    __syncthreads();
    int c = tid & 63, r = tid >> 6;
    int col = cg*64 + c;
    if (col < NOUT){
        float acc = bout[col];
        #pragma unroll 8
        for (int k = 0; k < NS; ++k) acc += sy[r][k]*Wout[(size_t)k*NOUT + col];
        pred[(size_t)(rg*4 + r)*NOUT + col] = acc;
    }
}

// log-softmax entropy + scatter outputs
__global__ void softout(const float* __restrict__ pred, float* __restrict__ out_pred,
                        float* __restrict__ out_cert, int t)
{
    __shared__ float red[8];
    int b = blockIdx.x, tid = threadIdx.x;
    float v[4];
    float m = -1e30f;
    for (int i = 0; i < 4; ++i){
        int n = tid + i*256;
        v[i] = (n < NOUT) ? pred[(size_t)b*NOUT + n] : -1e30f;
        m = fmaxf(m, v[i]);
    }
    for (int o = 32; o; o >>= 1) m = fmaxf(m, __shfl_xor(m, o, 64));
    if ((tid & 63) == 0) red[tid >> 6] = m;
    __syncthreads();
    m = fmaxf(fmaxf(red[0], red[1]), fmaxf(red[2], red[3]));
    __syncthreads();
    float s1 = 0.f, s2 = 0.f;
    for (int i = 0; i < 4; ++i){
        int n = tid + i*256;
        if (n < NOUT){
            float e = expf(v[i] - m);
            s1 += e; s2 += e*(v[i] - m);
        }
    }
    for (int o = 32; o; o >>= 1){ s1 += __shfl_xor(s1, o, 64); s2 += __shfl_xor(s2, o, 64); }
    if ((tid & 63) == 0){ red[tid >> 6] = s1; red[4 + (tid >> 6)] = s2; }
    __syncthreads();
    s1 = red[0]+red[1]+red[2]+red[3];
    s2 = red[4]+red[5]+red[6]+red[7];
    float plogp = s2/s1 - logf(s1);
    float ne = -plogp / logf((float)NOUT);
    for (int i = 0; i < 4; ++i){
        int n = tid + i*256;
        if (n < NOUT) out_pred[(size_t)b*NOUT*TT + (size_t)n*TT + t] = v[i];
    }
    if (tid == 0){
        out_cert[(size_t)b*2*TT + t]      = ne;
        out_cert[(size_t)b*2*TT + TT + t] = 1.f - ne;
    }
}

extern "C" void kernel_launch(void* const* d_in, const int* in_sizes, int n_in,
                              void* d_out, int out_size, void* d_ws, size_t ws_size,
                              hipStream_t stream)
{
    const float* x    = (const float*)d_in[0];
    const float* Wf   = (const float*)d_in[1];
    const float* bf   = (const float*)d_in[2];
    const float* stt  = (const float*)d_in[3];
    const float* ss   = (const float*)d_in[4];
    const float* dca  = (const float*)d_in[5];
    const float* dco  = (const float*)d_in[6];
    const float* Wqp  = (const float*)d_in[7];
    const float* bqp  = (const float*)d_in[8];
    const float* Wq   = (const float*)d_in[9];
    const float* bq   = (const float*)d_in[10];
    const float* Wk   = (const float*)d_in[11];
    const float* bk   = (const float*)d_in[12];
    const float* Wv   = (const float*)d_in[13];
    const float* bv   = (const float*)d_in[14];
    const float* Wo   = (const float*)d_in[15];
    const float* bo   = (const float*)d_in[16];
    const float* Ws1  = (const float*)d_in[17];
    const float* bs1  = (const float*)d_in[18];
    const float* lng  = (const float*)d_in[19];
    const float* lnb  = (const float*)d_in[20];
    const float* nw1  = (const float*)d_in[21];
    const float* nb1  = (const float*)d_in[22];
    const float* nw2  = (const float*)d_in[23];
    const float* nb2  = (const float*)d_in[24];
    const float* Wout = (const float*)d_in[25];
    const float* bout = (const float*)d_in[26];
    const int* ila = (const int*)d_in[27];
    const int* ira = (const int*)d_in[28];
    const int* ilo = (const int*)d_in[29];
    const int* iro = (const int*)d_in[30];

    float* ws = (float*)d_ws;
    float* Kb    = ws + OFF_K;
    float* Vb    = ws + OFF_V;
    float* Wfk   = ws + OFF_WFK;
    float* Wfv   = ws + OFF_WFV;
    float* Wc1   = ws + OFF_WC1;
    float* Wos1  = ws + OFF_WOS1;
    float* bfk   = ws + OFF_BFK;
    float* bfv   = ws + OFF_BFV;
    float* bc1   = ws + OFF_BC1;
    float* bc2   = ws + OFF_BC2;
    float* aA    = ws + OFF_AA;
    float* bA    = ws + OFF_BA;
    float* aO    = ws + OFF_AO;
    float* bO    = ws + OFF_BO;
    float* Qh    = ws + OFF_QH;
    float* att   = ws + OFF_ATT;
    float* hpart = ws + OFF_HPART;
    float* trace = ws + OFF_TRACE;
    float* act_t = ws + OFF_ACT;
    float* predb = ws + OFF_PRED;

    float* outp = (float*)d_out;
    float* out_pred = outp;
    float* out_cert = outp + (size_t)BB*NOUT*TT;
    float* out_syo  = out_cert + (size_t)BB*2*TT;

    // ---- setup: weight combos, K/V, initial state ----
    sgemm64<<<dim3(8,8),  256, 0, stream>>>(Wf, 512, Wk, 512, nullptr, Wfk, 512, 512);
    sgemm64<<<dim3(8,8),  256, 0, stream>>>(Wf, 512, Wv, 512, nullptr, Wfv, 512, 512);
    sgemm64<<<dim3(8,8),  256, 0, stream>>>(Wqp,512, Wq, 512, nullptr, Wc1, 512, 512);
    sgemm64<<<dim3(64,8), 256, 0, stream>>>(Wo, 512, Ws1, 4096, nullptr, Wos1, 4096, 512);
    bias_combo<<<2, 256, 0, stream>>>(bf,  Wk, 512, bk, bfk, 512);
    bias_combo<<<2, 256, 0, stream>>>(bf,  Wv, 512, bv, bfv, 512);
    bias_combo<<<2, 256, 0, stream>>>(bqp, Wq, 512, bq, bc1, 512);
    bias_combo<<<16,256, 0, stream>>>(bo,  Ws1,4096, bs1, bc2, 4096);
    sgemm64<<<dim3(8,64), 256, 0, stream>>>(x, 512, Wfk, 512, bfk, Kb, 512, 512);
    sgemm64<<<dim3(8,64), 256, 0, stream>>>(x, 512, Wfv, 512, bfv, Vb, 512, 512);
    init_state<<<512, 256, 0, stream>>>(ss, ilo, iro, act_t, aA, bA, aO, bO);

    const size_t SB = (size_t)BB*NS;
    for (int t = 0; t < TT; ++t){
        int rd = t & 1, wr = 1 - rd;
        qh_sync<<<dim3(8,16), 256, 0, stream>>>(act_t, aA + rd*SB, bA + rd*SB,
                                                aA + wr*SB, bA + wr*SB,
                                                ila, ira, dca, Wc1, bc1, Qh);
        attn_kernel<<<dim3(NH,BB), 64, 0, stream>>>(Qh, Kb, Vb, att);
        hgemm<<<dim3(64,8), 256, 0, stream>>>(att, act_t, Wos1, Ws1, hpart);
        gluln<<<BB, 256, 0, stream>>>(hpart, bc2, lng, lnb, trace, t);
        nlm<<<DM, 256, 0, stream>>>(trace, stt, nw1, nb1, nw2, nb2, act_t, t);
        pred_sync<<<dim3(16,16), 256, 0, stream>>>(act_t, aO + rd*SB, bO + rd*SB,
                                                   aO + wr*SB, bO + wr*SB,
                                                   ilo, iro, dco, Wout, bout,
                                                   predb, out_syo, t);
        softout<<<BB, 256, 0, stream>>>(predb, out_pred, out_cert, t);
    }
}

// Round 3
// 6127.747 us; speedup vs baseline: 1.3950x; 1.3950x over previous
//
#include <hip/hip_runtime.h>
#include <hip/hip_bf16.h>
#include <math.h>

#define BB 64
#define SS 64
#define DIN 512
#define DA 512
#define DM 2048
#define MM 25
#define NH 8
#define HD 64
#define NS 512
#define NOUT 1000
#define TT 50
#define HN 32
#define KTOT 2560
#define NOUT2 4096
#define KCH 640

typedef __attribute__((ext_vector_type(8))) short bf16x8_t;
typedef __attribute__((ext_vector_type(4))) float f32x4_t;

// ---------------- workspace layout (float units) ----------------
static const size_t OFF_K     = 0;                                  // bf16 BB*SS*DA
static const size_t OFF_V     = OFF_K + (size_t)BB*SS*DA/2;
static const size_t OFF_WCT   = OFF_V + (size_t)BB*SS*DA/2;         // bf16 4096*2560
static const size_t OFF_WFK   = OFF_WCT + (size_t)NOUT2*KTOT/2;
static const size_t OFF_WFV   = OFF_WFK + (size_t)DIN*DA;
static const size_t OFF_WC1   = OFF_WFV + (size_t)DIN*DA;
static const size_t OFF_BFK   = OFF_WC1 + (size_t)NS*DA;
static const size_t OFF_BFV   = OFF_BFK + DA;
static const size_t OFF_BC1   = OFF_BFV + DA;
static const size_t OFF_BC2   = OFF_BC1 + DA;
static const size_t OFF_AA    = OFF_BC2 + 2*DM;
static const size_t OFF_BA    = OFF_AA + (size_t)2*BB*NS;
static const size_t OFF_AO    = OFF_BA + (size_t)2*BB*NS;
static const size_t OFF_BO    = OFF_AO + (size_t)2*BB*NS;
static const size_t OFF_QH    = OFF_BO + (size_t)2*BB*NS;
static const size_t OFF_ATTB  = OFF_QH + (size_t)BB*DA;             // bf16 BB*DA
static const size_t OFF_ACTB  = OFF_ATTB + (size_t)BB*DA/2;         // bf16 BB*DM  [b][d]
static const size_t OFF_HPART = OFF_ACTB + (size_t)BB*DM/2;         // 4 chunks fp32
static const size_t OFF_TRACE = OFF_HPART + (size_t)4*BB*2*DM;
static const size_t OFF_ACT   = OFF_TRACE + (size_t)MM*DM*BB;       // fp32 [d][b]
static const size_t OFF_PRED  = OFF_ACT + (size_t)DM*BB;
static const size_t OFF_END   = OFF_PRED + (size_t)BB*NOUT;

__device__ inline float gelu_tanh(float x){
    float x3 = x*x*x;
    float u = 0.7978845608028654f*(x + 0.044715f*x3);
    return 0.5f*x*(1.0f + tanhf(u));
}

// ---------------- generic 64x64-tile fp32 GEMM (setup only) ----------------
__global__ void sgemm64(const float* __restrict__ A, int lda,
                        const float* __restrict__ Bm, int ldb,
                        const float* __restrict__ bias,
                        float* __restrict__ C, int ldc, int Kdim)
{
    __shared__ float la[16][65];
    __shared__ float lb[16][64];
    int cg = blockIdx.x, rg = blockIdx.y, tid = threadIdx.x;
    int tx = tid & 15, ty = tid >> 4;
    const float* Ab = A + (size_t)rg*64*lda;
    const float* Bb = Bm + (size_t)cg*64;
    float acc[4][4] = {};
    for (int k0 = 0; k0 < Kdim; k0 += 16){
        for (int i = tid; i < 1024; i += 256){
            int r = i >> 4, kk = i & 15;
            la[kk][r] = Ab[(size_t)r*lda + k0 + kk];
        }
        for (int i = tid; i < 1024; i += 256){
            int kk = i >> 6, c = i & 63;
            lb[kk][c] = Bb[(size_t)(k0+kk)*ldb + c];
        }
        __syncthreads();
        #pragma unroll
        for (int kk = 0; kk < 16; ++kk){
            float av[4], bv[4];
            #pragma unroll
            for (int i = 0; i < 4; ++i) av[i] = la[kk][ty*4+i];
            #pragma unroll
            for (int j = 0; j < 4; ++j) bv[j] = lb[kk][tx*4+j];
            #pragma unroll
            for (int i = 0; i < 4; ++i)
                #pragma unroll
                for (int j = 0; j < 4; ++j) acc[i][j] += av[i]*bv[j];
        }
        __syncthreads();
    }
    for (int i = 0; i < 4; ++i){
        int row = rg*64 + ty*4 + i;
        for (int j = 0; j < 4; ++j){
            int col = cg*64 + tx*4 + j;
            float v = acc[i][j];
            if (bias) v += bias[col];
            C[(size_t)row*ldc + col] = v;
        }
    }
}

// same GEMM but bf16 output (for K/V)
__global__ void sgemm64_bf16out(const float* __restrict__ A, int lda,
                                const float* __restrict__ Bm, int ldb,
                                const float* __restrict__ bias,
                                __hip_bfloat16* __restrict__ C, int ldc, int Kdim)
{
    __shared__ float la[16][65];
    __shared__ float lb[16][64];
    int cg = blockIdx.x, rg = blockIdx.y, tid = threadIdx.x;
    int tx = tid & 15, ty = tid >> 4;
    const float* Ab = A + (size_t)rg*64*lda;
    const float* Bb = Bm + (size_t)cg*64;
    float acc[4][4] = {};
    for (int k0 = 0; k0 < Kdim; k0 += 16){
        for (int i = tid; i < 1024; i += 256){
            int r = i >> 4, kk = i & 15;
            la[kk][r] = Ab[(size_t)r*lda + k0 + kk];
        }
        for (int i = tid; i < 1024; i += 256){
            int kk = i >> 6, c = i & 63;
            lb[kk][c] = Bb[(size_t)(k0+kk)*ldb + c];
        }
        __syncthreads();
        #pragma unroll
        for (int kk = 0; kk < 16; ++kk){
            float av[4], bv[4];
            #pragma unroll
            for (int i = 0; i < 4; ++i) av[i] = la[kk][ty*4+i];
            #pragma unroll
            for (int j = 0; j < 4; ++j) bv[j] = lb[kk][tx*4+j];
            #pragma unroll
            for (int i = 0; i < 4; ++i)
                #pragma unroll
                for (int j = 0; j < 4; ++j) acc[i][j] += av[i]*bv[j];
        }
        __syncthreads();
    }
    for (int i = 0; i < 4; ++i){
        int row = rg*64 + ty*4 + i;
        for (int j = 0; j < 4; ++j){
            int col = cg*64 + tx*4 + j;
            float v = acc[i][j];
            if (bias) v += bias[col];
            C[(size_t)row*ldc + col] = __float2bfloat16(v);
        }
    }
}

// C = Wo @ Ws1_top, stored TRANSPOSED bf16 into WcT[n][k] (k<512).  setup only.
__global__ void gemm_wos1_t(const float* __restrict__ Wo, const float* __restrict__ Ws1,
                            __hip_bfloat16* __restrict__ WcT)
{
    __shared__ float la[16][65];
    __shared__ float lb[16][64];
    int cg = blockIdx.x, rg = blockIdx.y, tid = threadIdx.x;   // cg over n (64), rg over k (8)
    int tx = tid & 15, ty = tid >> 4;
    const float* Ab = Wo + (size_t)rg*64*512;
    const float* Bb = Ws1 + (size_t)cg*64;
    float acc[4][4] = {};
    for (int k0 = 0; k0 < 512; k0 += 16){
        for (int i = tid; i < 1024; i += 256){
            int r = i >> 4, kk = i & 15;
            la[kk][r] = Ab[(size_t)r*512 + k0 + kk];
        }
        for (int i = tid; i < 1024; i += 256){
            int kk = i >> 6, c = i & 63;
            lb[kk][c] = Bb[(size_t)(k0+kk)*NOUT2 + c];
        }
        __syncthreads();
        #pragma unroll
        for (int kk = 0; kk < 16; ++kk){
            float av[4], bv[4];
            #pragma unroll
            for (int i = 0; i < 4; ++i) av[i] = la[kk][ty*4+i];
            #pragma unroll
            for (int j = 0; j < 4; ++j) bv[j] = lb[kk][tx*4+j];
            #pragma unroll
            for (int i = 0; i < 4; ++i)
                #pragma unroll
                for (int j = 0; j < 4; ++j) acc[i][j] += av[i]*bv[j];
        }
        __syncthreads();
    }
    for (int i = 0; i < 4; ++i){
        int krow = rg*64 + ty*4 + i;
        for (int j = 0; j < 4; ++j){
            int ncol = cg*64 + tx*4 + j;
            WcT[(size_t)ncol*KTOT + krow] = __float2bfloat16(acc[i][j]);
        }
    }
}

// transpose+convert Ws1 rows 512..2559 into WcT[n][512+r]
__global__ void tcvt_ws1(const float* __restrict__ Ws1, __hip_bfloat16* __restrict__ WcT)
{
    __shared__ float tile[32][33];
    int bx = blockIdx.x;          // n tile (128)
    int by = blockIdx.y;          // r tile (64)
    int tx = threadIdx.x & 31, ty = threadIdx.x >> 5;  // 32x8
    for (int i = 0; i < 4; ++i){
        int r = by*32 + ty + i*8;
        tile[ty + i*8][tx] = Ws1[(size_t)(512 + r)*NOUT2 + bx*32 + tx];
    }
    __syncthreads();
    for (int i = 0; i < 4; ++i){
        int n = bx*32 + ty + i*8;
        int r = by*32 + tx;
        WcT[(size_t)n*KTOT + 512 + r] = __float2bfloat16(tile[tx][ty + i*8]);
    }
}

// out[n] = sum_k bvec[k]*W[k,n] + badd[n],  K fixed = 512
__global__ void bias_combo(const float* __restrict__ bvec, const float* __restrict__ W,
                           int ldw, const float* __restrict__ badd,
                           float* __restrict__ out, int N)
{
    int n = blockIdx.x*256 + threadIdx.x;
    if (n >= N) return;
    float acc = badd[n];
    for (int k = 0; k < 512; ++k) acc += bvec[k]*W[(size_t)k*ldw + n];
    out[n] = acc;
}

__global__ void init_state(const float* __restrict__ ss,
                           const int* __restrict__ ilo, const int* __restrict__ iro,
                           float* __restrict__ act_t,
                           float* __restrict__ aA0, float* __restrict__ bA0,
                           float* __restrict__ aO0, float* __restrict__ bO0,
                           __hip_bfloat16* __restrict__ act_bfT)
{
    int i = blockIdx.x*256 + threadIdx.x;
    if (i < BB*DM){
        int d = i >> 6, b = i & 63;
        float v = ss[d];
        act_t[i] = v;
        act_bfT[(size_t)b*DM + d] = __float2bfloat16(v);
    }
    if (i < BB*NS){
        int j = i & (NS-1);
        aA0[i] = 0.f; bA0[i] = 0.f;
        aO0[i] = ss[ilo[j]]*ss[iro[j]];
        bO0[i] = 1.f;
    }
}

// fused syncA + Qh = syA@Wc1 + bc1
__global__ void qh_sync(const float* __restrict__ act_t,
                        const float* __restrict__ aAold, const float* __restrict__ bAold,
                        float* __restrict__ aAnew, float* __restrict__ bAnew,
                        const int* __restrict__ il, const int* __restrict__ ir,
                        const float* __restrict__ decay,
                        const float* __restrict__ Wc1, const float* __restrict__ bc1,
                        float* __restrict__ Qh)
{
    __shared__ float sy[4][NS];
    int cg = blockIdx.x, rg = blockIdx.y, tid = threadIdx.x;
    for (int i = tid; i < 4*NS; i += 256){
        int r = i >> 9, j = i & (NS-1);
        int b = rg*4 + r;
        float pair = act_t[(size_t)il[j]*BB + b] * act_t[(size_t)ir[j]*BB + b];
        float rr = expf(-fminf(fmaxf(decay[j], 0.f), 15.f));
        float a  = rr*aAold[b*NS + j] + pair;
        float be = rr*bAold[b*NS + j] + 1.f;
        sy[r][j] = a * rsqrtf(be);
        if (cg == 0){ aAnew[b*NS + j] = a; bAnew[b*NS + j] = be; }
    }
    __syncthreads();
    int c = tid & 63, r = tid >> 6;
    int col = cg*64 + c;
    float acc = bc1[col];
    #pragma unroll 8
    for (int k = 0; k < NS; ++k) acc += sy[r][k]*Wc1[(size_t)k*DA + col];
    Qh[(size_t)(rg*4 + r)*DA + col] = acc;
}

// attention per (h,b), bf16 K/V, bf16 output
__global__ void attn_kernel(const float* __restrict__ Qh, const __hip_bfloat16* __restrict__ Kb,
                            const __hip_bfloat16* __restrict__ Vb, __hip_bfloat16* __restrict__ att)
{
    __shared__ float q[HD];
    __shared__ float kt[SS][HD+1];
    __shared__ float w[SS];
    int h = blockIdx.x, b = blockIdx.y, lane = threadIdx.x;
    q[lane] = Qh[(size_t)b*DA + h*HD + lane];
    for (int i = lane; i < SS*HD; i += 64){
        int s = i >> 6, d = i & 63;
        kt[s][d] = __bfloat162float(Kb[((size_t)(b*SS + s))*DA + h*HD + d]);
    }
    __syncthreads();
    float sc = 0.f;
    #pragma unroll 8
    for (int d = 0; d < HD; ++d) sc += q[d]*kt[lane][d];
    sc *= 0.125f;
    float m = sc;
    for (int o = 32; o; o >>= 1) m = fmaxf(m, __shfl_xor(m, o, 64));
    float e = expf(sc - m);
    float sum = e;
    for (int o = 32; o; o >>= 1) sum += __shfl_xor(sum, o, 64);
    w[lane] = e / sum;
    __syncthreads();
    float o = 0.f;
    #pragma unroll 8
    for (int s = 0; s < SS; ++s) o += w[s]*__bfloat162float(Vb[((size_t)(b*SS + s))*DA + h*HD + lane]);
    att[(size_t)b*DA + h*HD + lane] = __float2bfloat16(o);
}

// bf16 MFMA GEMM: h = [att | act] @ WcT^T, split-K x4.  grid(64,4), 256 thr.
__global__ __launch_bounds__(256) void hgemm_mfma(const __hip_bfloat16* __restrict__ att_bf,
                                                  const __hip_bfloat16* __restrict__ act_bfT,
                                                  const __hip_bfloat16* __restrict__ WcT,
                                                  float* __restrict__ hpart)
{
    __shared__ unsigned short Al[64][40];
    __shared__ unsigned short Bl[64][40];
    int cg = blockIdx.x, kc = blockIdx.y, tid = threadIdx.x;
    int w = tid >> 6, lane = tid & 63;
    int srow = tid >> 2;            // staging row 0..63
    int skg  = (tid & 3) * 8;       // staging k offset 0,8,16,24
    int n0 = cg*64;
    f32x4_t acc[4];
    #pragma unroll
    for (int t2 = 0; t2 < 4; ++t2) acc[t2] = (f32x4_t){0.f,0.f,0.f,0.f};

    const unsigned short* attu = (const unsigned short*)att_bf;
    const unsigned short* actu = (const unsigned short*)act_bfT;
    const unsigned short* wctu = (const unsigned short*)WcT;

    for (int step = 0; step < 20; ++step){
        int k0 = kc*KCH + step*32;
        // stage B tile (n x k) from WcT — contiguous 16B per thread
        uint4 bv = *reinterpret_cast<const uint4*>(&wctu[(size_t)(n0+srow)*KTOT + k0 + skg]);
        *reinterpret_cast<uint4*>(&Bl[srow][skg]) = bv;
        // stage A tile (b x k)
        uint4 av;
        if (k0 < 512) av = *reinterpret_cast<const uint4*>(&attu[(size_t)srow*DA + k0 + skg]);
        else          av = *reinterpret_cast<const uint4*>(&actu[(size_t)srow*DM + (k0-512) + skg]);
        *reinterpret_cast<uint4*>(&Al[srow][skg]) = av;
        __syncthreads();
        bf16x8_t af = *reinterpret_cast<const bf16x8_t*>(&Al[w*16 + (lane&15)][(lane>>4)*8]);
        #pragma unroll
        for (int t2 = 0; t2 < 4; ++t2){
            bf16x8_t bf = *reinterpret_cast<const bf16x8_t*>(&Bl[t2*16 + (lane&15)][(lane>>4)*8]);
            acc[t2] = __builtin_amdgcn_mfma_f32_16x16x32_bf16(af, bf, acc[t2], 0, 0, 0);
        }
        __syncthreads();
    }
    float* out = hpart + (size_t)kc*BB*2*DM;
    int colb = lane & 15, rg2 = (lane >> 4)*4;
    #pragma unroll
    for (int t2 = 0; t2 < 4; ++t2){
        #pragma unroll
        for (int r = 0; r < 4; ++r){
            int row = w*16 + rg2 + r;
            int col = n0 + t2*16 + colb;
            out[(size_t)row*2*DM + col] = acc[t2][r];
        }
    }
}

// GLU + LayerNorm over 4 split-K partials, write into circular trace slot
__global__ void gluln(const float* __restrict__ hpart, const float* __restrict__ bc2,
                      const float* __restrict__ g, const float* __restrict__ bta,
                      float* __restrict__ trace, int t)
{
    __shared__ float red[8];
    int b = blockIdx.x, tid = threadIdx.x;
    float sv[8];
    float lsum = 0.f, lsq = 0.f;
    for (int i = 0; i < 8; ++i){
        int n = tid + i*256;
        float h1 = bc2[n], h2 = bc2[DM + n];
        #pragma unroll
        for (int c = 0; c < 4; ++c){
            const float* hp = hpart + (size_t)c*BB*2*DM + (size_t)b*2*DM;
            h1 += hp[n];
            h2 += hp[DM + n];
        }
        float s = h1 * (1.f/(1.f + expf(-h2)));
        sv[i] = s; lsum += s; lsq += s*s;
    }
    for (int o = 32; o; o >>= 1){ lsum += __shfl_down(lsum, o, 64); lsq += __shfl_down(lsq, o, 64); }
    int wid = tid >> 6;
    if ((tid & 63) == 0){ red[wid] = lsum; red[4 + wid] = lsq; }
    __syncthreads();
    float tsum = red[0]+red[1]+red[2]+red[3];
    float tsq  = red[4]+red[5]+red[6]+red[7];
    float mu = tsum/DM;
    float var = tsq/DM - mu*mu;
    float inv = rsqrtf(var + 1e-5f);
    int slot = t % MM;
    float* tr = trace + (size_t)slot*DM*BB;
    for (int i = 0; i < 8; ++i){
        int n = tid + i*256;
        float st = (sv[i] - mu)*inv*g[n] + bta[n];
        tr[(size_t)n*BB + b] = st;
    }
}

// neuron-level models; writes act fp32 [d][b] AND bf16 [b][d]
__global__ void nlm(const float* __restrict__ trace, const float* __restrict__ stt,
                    const float* __restrict__ nw1, const float* __restrict__ nb1,
                    const float* __restrict__ nw2, const float* __restrict__ nb2,
                    float* __restrict__ act_t, __hip_bfloat16* __restrict__ act_bfT, int t)
{
    __shared__ float w1[MM][HN];
    __shared__ float tr[MM][BB];
    __shared__ float w2[HN];
    __shared__ float b1[HN];
    __shared__ float red[4][BB];
    int d = blockIdx.x, tid = threadIdx.x;
    for (int i = tid; i < MM*HN; i += 256) w1[i/HN][i%HN] = nw1[(size_t)d*MM*HN + i];
    if (tid < HN){ w2[tid] = nw2[d*HN + tid]; b1[tid] = nb1[d*HN + tid]; }
    for (int i = tid; i < MM*BB; i += 256){
        int m = i >> 6, b = i & 63;
        int time = t - (MM-1) + m;
        float v;
        if (time >= 0) v = trace[(size_t)(time % MM)*DM*BB + (size_t)d*BB + b];
        else           v = stt[(size_t)d*MM + (m + t + 1)];
        tr[m][b] = v;
    }
    __syncthreads();
    int b = tid & 63, hg = tid >> 6;
    float pa = 0.f;
    #pragma unroll
    for (int hh = 0; hh < 8; ++hh){
        int h = hg*8 + hh;
        float a = b1[h];
        #pragma unroll
        for (int m = 0; m < MM; ++m) a += tr[m][b]*w1[m][h];
        pa += gelu_tanh(a)*w2[h];
    }
    red[hg][b] = pa;
    __syncthreads();
    if (tid < 64){
        float v = red[0][tid] + red[1][tid] + red[2][tid] + red[3][tid] + nb2[d];
        act_t[(size_t)d*BB + tid] = v;
        act_bfT[(size_t)tid*DM + d] = __float2bfloat16(v);
    }
}

// fused syncO + pred = syO@Wout + bout
__global__ void pred_sync(const float* __restrict__ act_t,
                          const float* __restrict__ aOold, const float* __restrict__ bOold,
                          float* __restrict__ aOnew, float* __restrict__ bOnew,
                          const int* __restrict__ ilo, const int* __restrict__ iro,
                          const float* __restrict__ decay,
                          const float* __restrict__ Wout, const float* __restrict__ bout,
                          float* __restrict__ pred, float* __restrict__ syo_out, int t)
{
    __shared__ float sy[4][NS];
    int cg = blockIdx.x, rg = blockIdx.y, tid = threadIdx.x;
    for (int i = tid; i < 4*NS; i += 256){
        int r = i >> 9, j = i & (NS-1);
        int b = rg*4 + r;
        float pair = act_t[(size_t)ilo[j]*BB + b] * act_t[(size_t)iro[j]*BB + b];
        float rr = expf(-fminf(fmaxf(decay[j], 0.f), 15.f));
        float a  = rr*aOold[b*NS + j] + pair;
        float be = rr*bOold[b*NS + j] + 1.f;
        float s = a * rsqrtf(be);
        sy[r][j] = s;
        if (cg == 0){
            aOnew[b*NS + j] = a; bOnew[b*NS + j] = be;
            if (t == TT-1) syo_out[b*NS + j] = s;
        }
    }
    __syncthreads();
    int c = tid & 63, r = tid >> 6;
    int col = cg*64 + c;
    if (col < NOUT){
        float acc = bout[col];
        #pragma unroll 8
        for (int k = 0; k < NS; ++k) acc += sy[r][k]*Wout[(size_t)k*NOUT + col];
        pred[(size_t)(rg*4 + r)*NOUT + col] = acc;
    }
}

// log-softmax entropy + scatter outputs
__global__ void softout(const float* __restrict__ pred, float* __restrict__ out_pred,
                        float* __restrict__ out_cert, int t)
{
    __shared__ float red[8];
    int b = blockIdx.x, tid = threadIdx.x;
    float v[4];
    float m = -1e30f;
    for (int i = 0; i < 4; ++i){
        int n = tid + i*256;
        v[i] = (n < NOUT) ? pred[(size_t)b*NOUT + n] : -1e30f;
        m = fmaxf(m, v[i]);
    }
    for (int o = 32; o; o >>= 1) m = fmaxf(m, __shfl_xor(m, o, 64));
    if ((tid & 63) == 0) red[tid >> 6] = m;
    __syncthreads();
    m = fmaxf(fmaxf(red[0], red[1]), fmaxf(red[2], red[3]));
    __syncthreads();
    float s1 = 0.f, s2 = 0.f;
    for (int i = 0; i < 4; ++i){
        int n = tid + i*256;
        if (n < NOUT){
            float e = expf(v[i] - m);
            s1 += e; s2 += e*(v[i] - m);
        }
    }
    for (int o = 32; o; o >>= 1){ s1 += __shfl_xor(s1, o, 64); s2 += __shfl_xor(s2, o, 64); }
    if ((tid & 63) == 0){ red[tid >> 6] = s1; red[4 + (tid >> 6)] = s2; }
    __syncthreads();
    s1 = red[0]+red[1]+red[2]+red[3];
    s2 = red[4]+red[5]+red[6]+red[7];
    float plogp = s2/s1 - logf(s1);
    float ne = -plogp / logf((float)NOUT);
    for (int i = 0; i < 4; ++i){
        int n = tid + i*256;
        if (n < NOUT) out_pred[(size_t)b*NOUT*TT + (size_t)n*TT + t] = v[i];
    }
    if (tid == 0){
        out_cert[(size_t)b*2*TT + t]      = ne;
        out_cert[(size_t)b*2*TT + TT + t] = 1.f - ne;
    }
}

extern "C" void kernel_launch(void* const* d_in, const int* in_sizes, int n_in,
                              void* d_out, int out_size, void* d_ws, size_t ws_size,
                              hipStream_t stream)
{
    const float* x    = (const float*)d_in[0];
    const float* Wf   = (const float*)d_in[1];
    const float* bf   = (const float*)d_in[2];
    const float* stt  = (const float*)d_in[3];
    const float* ss   = (const float*)d_in[4];
    const float* dca  = (const float*)d_in[5];
    const float* dco  = (const float*)d_in[6];
    const float* Wqp  = (const float*)d_in[7];
    const float* bqp  = (const float*)d_in[8];
    const float* Wq   = (const float*)d_in[9];
    const float* bq   = (const float*)d_in[10];
    const float* Wk   = (const float*)d_in[11];
    const float* bk   = (const float*)d_in[12];
    const float* Wv   = (const float*)d_in[13];
    const float* bv   = (const float*)d_in[14];
    const float* Wo   = (const float*)d_in[15];
    const float* bo   = (const float*)d_in[16];
    const float* Ws1  = (const float*)d_in[17];
    const float* bs1  = (const float*)d_in[18];
    const float* lng  = (const float*)d_in[19];
    const float* lnb  = (const float*)d_in[20];
    const float* nw1  = (const float*)d_in[21];
    const float* nb1  = (const float*)d_in[22];
    const float* nw2  = (const float*)d_in[23];
    const float* nb2  = (const float*)d_in[24];
    const float* Wout = (const float*)d_in[25];
    const float* bout = (const float*)d_in[26];
    const int* ila = (const int*)d_in[27];
    const int* ira = (const int*)d_in[28];
    const int* ilo = (const int*)d_in[29];
    const int* iro = (const int*)d_in[30];

    float* ws = (float*)d_ws;
    __hip_bfloat16* Kb     = (__hip_bfloat16*)(ws + OFF_K);
    __hip_bfloat16* Vb     = (__hip_bfloat16*)(ws + OFF_V);
    __hip_bfloat16* WcT    = (__hip_bfloat16*)(ws + OFF_WCT);
    float* Wfk   = ws + OFF_WFK;
    float* Wfv   = ws + OFF_WFV;
    float* Wc1   = ws + OFF_WC1;
    float* bfk   = ws + OFF_BFK;
    float* bfv   = ws + OFF_BFV;
    float* bc1   = ws + OFF_BC1;
    float* bc2   = ws + OFF_BC2;
    float* aA    = ws + OFF_AA;
    float* bA    = ws + OFF_BA;
    float* aO    = ws + OFF_AO;
    float* bO    = ws + OFF_BO;
    float* Qh    = ws + OFF_QH;
    __hip_bfloat16* att_bf = (__hip_bfloat16*)(ws + OFF_ATTB);
    __hip_bfloat16* act_bf = (__hip_bfloat16*)(ws + OFF_ACTB);
    float* hpart = ws + OFF_HPART;
    float* trace = ws + OFF_TRACE;
    float* act_t = ws + OFF_ACT;
    float* predb = ws + OFF_PRED;

    float* outp = (float*)d_out;
    float* out_pred = outp;
    float* out_cert = outp + (size_t)BB*NOUT*TT;
    float* out_syo  = out_cert + (size_t)BB*2*TT;

    // ---- setup ----
    sgemm64<<<dim3(8,8),  256, 0, stream>>>(Wf, 512, Wk, 512, nullptr, Wfk, 512, 512);
    sgemm64<<<dim3(8,8),  256, 0, stream>>>(Wf, 512, Wv, 512, nullptr, Wfv, 512, 512);
    sgemm64<<<dim3(8,8),  256, 0, stream>>>(Wqp,512, Wq, 512, nullptr, Wc1, 512, 512);
    gemm_wos1_t<<<dim3(64,8), 256, 0, stream>>>(Wo, Ws1, WcT);
    tcvt_ws1<<<dim3(128,64), 256, 0, stream>>>(Ws1, WcT);
    bias_combo<<<2, 256, 0, stream>>>(bf,  Wk, 512, bk, bfk, 512);
    bias_combo<<<2, 256, 0, stream>>>(bf,  Wv, 512, bv, bfv, 512);
    bias_combo<<<2, 256, 0, stream>>>(bqp, Wq, 512, bq, bc1, 512);
    bias_combo<<<16,256, 0, stream>>>(bo,  Ws1,4096, bs1, bc2, 4096);
    sgemm64_bf16out<<<dim3(8,64), 256, 0, stream>>>(x, 512, Wfk, 512, bfk, Kb, 512, 512);
    sgemm64_bf16out<<<dim3(8,64), 256, 0, stream>>>(x, 512, Wfv, 512, bfv, Vb, 512, 512);
    init_state<<<512, 256, 0, stream>>>(ss, ilo, iro, act_t, aA, bA, aO, bO, act_bf);

    const size_t SB = (size_t)BB*NS;
    for (int t = 0; t < TT; ++t){
        int rd = t & 1, wr = 1 - rd;
        qh_sync<<<dim3(8,16), 256, 0, stream>>>(act_t, aA + rd*SB, bA + rd*SB,
                                                aA + wr*SB, bA + wr*SB,
                                                ila, ira, dca, Wc1, bc1, Qh);
        attn_kernel<<<dim3(NH,BB), 64, 0, stream>>>(Qh, Kb, Vb, att_bf);
        hgemm_mfma<<<dim3(64,4), 256, 0, stream>>>(att_bf, act_bf, WcT, hpart);
        gluln<<<BB, 256, 0, stream>>>(hpart, bc2, lng, lnb, trace, t);
        nlm<<<DM, 256, 0, stream>>>(trace, stt, nw1, nb1, nw2, nb2, act_t, act_bf, t);
        pred_sync<<<dim3(16,16), 256, 0, stream>>>(act_t, aO + rd*SB, bO + rd*SB,
                                                   aO + wr*SB, bO + wr*SB,
                                                   ilo, iro, dco, Wout, bout,
                                                   predb, out_syo, t);
        softout<<<BB, 256, 0, stream>>>(predb, out_pred, out_cert, t);
    }
}